// Round 17
// baseline (712.932 us; speedup 1.0000x reference)
//
#include <hip/hip_runtime.h>
#include <hip/hip_bf16.h>

// Problem constants
#define BB   64
#define SS   2048
#define MM   (BB*SS)      // 131072
#define NN   1024         // A
#define KK   1024         // AD = QD

typedef short bf16x8s __attribute__((ext_vector_type(8)));
typedef float f32x4   __attribute__((ext_vector_type(4)));

__device__ __forceinline__ short f2bf(float f) {
    union { __hip_bfloat16 h; short s; } u;
    u.h = __float2bfloat16(f);
    return u.s;
}

__device__ __forceinline__ bf16x8s cvt8v(f32x4 a, f32x4 b) {
    bf16x8s r;
    r[0] = f2bf(a[0]); r[1] = f2bf(a[1]); r[2] = f2bf(a[2]); r[3] = f2bf(a[3]);
    r[4] = f2bf(b[0]); r[5] = f2bf(b[1]); r[6] = f2bf(b[2]); r[7] = f2bf(b[3]);
    return r;
}

__device__ __forceinline__ bf16x8s cvt8(float4 a, float4 b) {
    bf16x8s r;
    r[0] = f2bf(a.x); r[1] = f2bf(a.y); r[2] = f2bf(a.z); r[3] = f2bf(a.w);
    r[4] = f2bf(b.x); r[5] = f2bf(b.y); r[6] = f2bf(b.z); r[7] = f2bf(b.w);
    return r;
}

__device__ __forceinline__ float tanh_fast(float x) {
    x = fminf(8.0f, fmaxf(-8.0f, x));
    float e = __expf(2.0f * x);
    return 1.0f - 2.0f * __builtin_amdgcn_rcpf(e + 1.0f);
}

__device__ __forceinline__ void load_lds16(const void* g, void* l) {
    __builtin_amdgcn_global_load_lds(
        (const __attribute__((address_space(1))) unsigned int*)g,
        (__attribute__((address_space(3))) unsigned int*)l,
        16, 0, 0);
}

// ---------------------------------------------------------------------------
// Kernel 0: f32 -> bf16 convert (W_pre only, 4MB), nontemporal stream.
// ---------------------------------------------------------------------------
__global__ void cvt_bf16_kernel(const float* __restrict__ src,
                                __hip_bfloat16* __restrict__ dst, int n8) {
    int i = blockIdx.x * blockDim.x + threadIdx.x;
    const int stride = gridDim.x * blockDim.x;
    const f32x4* s4 = (const f32x4*)src;
    bf16x8s* d8 = (bf16x8s*)dst;
    for (; i < n8; i += stride) {
        f32x4 a = __builtin_nontemporal_load(&s4[i * 2]);
        f32x4 b = __builtin_nontemporal_load(&s4[i * 2 + 1]);
        __builtin_nontemporal_store(cvt8v(a, b), &d8[i]);
    }
}

// ---------------------------------------------------------------------------
// Kernel 1: targetT[b][n] = sum_q input[b][q] * W_q[n][q]
// ---------------------------------------------------------------------------
__global__ void targetT_kernel(const float* __restrict__ input,
                               const float* __restrict__ W_q,
                               float* __restrict__ tgt) {
    __shared__ float inp[KK];
    const int t = threadIdx.x;
    const int b = blockIdx.x;
    const float* inRow = input + (size_t)b * KK;
    for (int i = t; i < KK; i += 256) inp[i] = inRow[i];
    __syncthreads();
    const int w = t >> 6, lane = t & 63;
    const int nbase = blockIdx.y * 256 + w * 64;
    for (int i = 0; i < 64; i++) {
        const int n = nbase + i;
        const float* wq = W_q + (size_t)n * KK;
        float a = 0.f;
        #pragma unroll
        for (int j = 0; j < 16; j++) a += wq[lane + 64 * j] * inp[lane + 64 * j];
        #pragma unroll
        for (int o = 32; o; o >>= 1) a += __shfl_xor(a, o);
        if (lane == 0) tgt[(size_t)b * NN + n] = a;
    }
}

// ---------------------------------------------------------------------------
// Kernel 2: 256x128 GEMM, A staged DIRECTLY as f32 from ctx (no cvt pass),
// converted to bf16 at fragment read. Fixes r11's two root causes:
//  (1) swizzle: (row&15)<<4 on 256B f32 rows -> 16 rows x 16 slots, every
//      bank-quad gets exactly 8 lanes (balanced, like the verified bf16
//      (row&7)<<4 which measures 0 conflicts). r11's (row&7)<<5 left bit4
//      unused -> 2x imbalance -> 3.27e8 conflicts.
//  (2) pipeline: r16's counted-vmcnt ledger (A 1-ahead, B 2-ahead, vmcnt(2)
//      at Ph2/Ph4 ends) instead of r11's vmcnt(0)-per-tile drain.
// LDS 160KB: A 2x64KB (256r x 256B) + B 2x16KB (128r x 128B bf16).
// 8 waves (4M x 2N), 64x64 out/wave, acc[4][4] (64 AGPR) -- r16-level VGPR.
// LDS-read bytes/tile/CU = 192KB, identical to r16.
// ---------------------------------------------------------------------------
__global__ __launch_bounds__(512, 2) void gemm_f32a_kernel(
    const float* __restrict__ ctx,            // [MM][KK] f32
    const __hip_bfloat16* __restrict__ wpb,   // [NN][KK] bf16
    const float* __restrict__ bpre,           // [NN]
    const float* __restrict__ tgt,            // [BB][NN]
    const float* __restrict__ vvec,           // [NN]
    float* __restrict__ pre,                  // [MM][NN]
    float* __restrict__ energy16)             // [16][MM] partials
{
    __shared__ __align__(16) char lds[163840];
    // A bufs: 0, 65536; B bufs: 131072, 147456.

    const int nwg  = gridDim.x;               // 4096, %8==0
    const int orig = blockIdx.x;
    const int swz  = (orig & 7) * (nwg >> 3) + (orig >> 3);
    const int mTile = swz >> 3;               // 0..511
    const int nTile = swz & 7;                // 0..7
    const int blockM = mTile * 256;
    const int blockN = nTile * 128;

    const int t = threadIdx.x, w = t >> 6, lane = t & 63;
    const int wm = w >> 1, wn = w & 1;        // 4 x 2 waves
    const int l15 = lane & 15;

    // ---- A staging: 8 instrs x 8KB. Thread t covers LDS row j*32+(t>>4),
    // physc (t&15)*16; source pre-swizzled with (row&15)<<4 (row&15=(t>>4)&15).
    const int ar  = t >> 4;                                    // 0..31
    const int alogc = ((t & 15) * 16) ^ ((ar & 15) << 4);
    const char* aSrc = (const char*)ctx + (size_t)(blockM + ar) * 4096 + alogc;
#define STAGE_AT(buf, T) do { \
    _Pragma("unroll") \
    for (int j = 0; j < 8; j++) \
        load_lds16(aSrc + (T)*256 + j*131072, &lds[(buf) + j*8192 + w*1024]); \
} while(0)

    // ---- B staging: 2 instrs. Thread t covers LDS row j*64+(t>>3); source
    // pre-swizzled with (row&7)<<4 (row&7=(t>>3)&7). (r16-verified pattern.)
    const int br  = t >> 3;                                    // 0..63
    const int blogc = ((t & 7) * 16) ^ ((br & 7) << 4);
    const char* bSrc = (const char*)wpb + (size_t)(blockN + br) * 2048 + blogc;
#define STAGE_BT(buf, T) do { \
    load_lds16(bSrc + (T)*128,          &lds[(buf) +        w*1024]); \
    load_lds16(bSrc + (T)*128 + 131072, &lds[(buf) + 8192 + w*1024]); \
} while(0)

    // ---- fragment read addressing ----
    const int aq  = (lane >> 4) * 32;          // f32 k-group byte offset
    const int swA = l15 << 4;                  // rA&15 == l15
    const int aRd = wm * 16384 + l15 * 256;    // + buf + mf*4096
    int aoff[2][2];
    aoff[0][0] = aq ^ swA;          aoff[0][1] = (aq + 16) ^ swA;
    aoff[1][0] = (128 + aq) ^ swA;  aoff[1][1] = (128 + aq + 16) ^ swA;

    const int c16 = (lane >> 4) * 16;          // bf16 k-group byte offset
    const int swB = (l15 & 7) << 4;
    const int bRd = wn * 8192 + l15 * 128;     // + bufB + nf*2048
    const int bk0 = c16 ^ swB, bk1 = (64 + c16) ^ swB;

    bf16x8s curA[4][2], Bf[4][2];

#define READ_CVT_A(buf, MF) do { \
    _Pragma("unroll") \
    for (int mm = 0; mm < 2; mm++) { \
        const int rb = (buf) + aRd + ((MF) + mm) * 4096; \
        _Pragma("unroll") \
        for (int ks = 0; ks < 2; ks++) { \
            float4 x0 = *(const float4*)&lds[rb + aoff[ks][0]]; \
            float4 x1 = *(const float4*)&lds[rb + aoff[ks][1]]; \
            curA[(MF) + mm][ks] = cvt8(x0, x1); \
        } } } while(0)
#define READ_B(bufb) do { \
    _Pragma("unroll") \
    for (int nf = 0; nf < 4; nf++) { \
        Bf[nf][0] = *(const bf16x8s*)&lds[(bufb) + bRd + nf * 2048 + bk0]; \
        Bf[nf][1] = *(const bf16x8s*)&lds[(bufb) + bRd + nf * 2048 + bk1]; \
    } } while(0)

    f32x4 acc[4][4];
    #pragma unroll
    for (int m = 0; m < 4; m++)
        #pragma unroll
        for (int n = 0; n < 4; n++)
            acc[m][n] = f32x4{0.f, 0.f, 0.f, 0.f};

    // 16-MFMA cluster (2 mf rows x 4 nf x 2 ks), setprio like r16.
#define MFMA_P(MF) do { \
    __builtin_amdgcn_s_setprio(1); \
    _Pragma("unroll") \
    for (int ks = 0; ks < 2; ks++) \
        _Pragma("unroll") \
        for (int mm = 0; mm < 2; mm++) \
            _Pragma("unroll") \
            for (int nf = 0; nf < 4; nf++) \
                acc[(MF)+mm][nf] = __builtin_amdgcn_mfma_f32_16x16x32_bf16( \
                    curA[(MF)+mm][ks], Bf[nf][ks], acc[(MF)+mm][nf], 0, 0, 0); \
    __builtin_amdgcn_s_setprio(0); \
} while(0)

#define BAR() do { __builtin_amdgcn_sched_barrier(0); \
    __builtin_amdgcn_s_barrier(); \
    __builtin_amdgcn_sched_barrier(0); } while(0)
#define VMCNT(n) asm volatile("s_waitcnt vmcnt(" #n ")")

    // ---- prologue: A(0)->A0 [8], B(0)->B0 [2], B(1)->B1 [2] ----
    STAGE_AT(0, 0);
    STAGE_BT(131072, 0);
    STAGE_BT(147456, 1);
    VMCNT(2);                      // A(0),B(0) landed; B(1) 2 in flight
    BAR();

    // K-tiles 0..13 in loop (i=0..6); tiles e=2i (A0/B0), o=2i+1 (A1/B1).
    //  Ph1: {read A(e)mf0-1 + B(e); stage A(o)->A1 [8];  MFMA mf0-1}      BAR
    //  Ph2: {read A(e)mf2-3;        stage B(e+2)->B0 [2]; MFMA; vmcnt(2)} BAR
    //  Ph3: {read A(o)mf0-1 + B(o); stage A(e+2)->A0 [8]; MFMA}           BAR
    //  Ph4: {read A(o)mf2-3;        stage B(o+2)->B1 [2]; MFMA; vmcnt(2)} BAR
    #pragma unroll 1
    for (int i = 0; i < 7; i++) {
        const int To = 2 * i + 1, Te2 = 2 * i + 2, To2 = 2 * i + 3;
        // Ph1
        READ_CVT_A(0, 0); READ_B(131072);
        STAGE_AT(65536, To);
        MFMA_P(0);
        BAR();
        // Ph2
        READ_CVT_A(0, 2);
        STAGE_BT(131072, Te2);     // B0 freed at Ph1 (barrier-separated)
        MFMA_P(2);
        VMCNT(2);                  // A(o),B(o) landed; B(e+2) 2 in flight
        BAR();
        // Ph3
        READ_CVT_A(65536, 0); READ_B(147456);
        STAGE_AT(0, Te2);          // A0 freed at Ph2
        MFMA_P(0);
        BAR();
        // Ph4
        READ_CVT_A(65536, 2);
        STAGE_BT(147456, To2);     // B1 freed at Ph3
        MFMA_P(2);
        VMCNT(2);                  // A(e+2),B(e+2) landed; B(o+2) in flight
        BAR();
    }

    // ---- peel: tiles 14 (A0/B0), 15 (A1/B1) ----
    READ_CVT_A(0, 0); READ_B(131072);
    STAGE_AT(65536, 15);           // A(15) still needs staging
    MFMA_P(0);
    BAR();
    READ_CVT_A(0, 2);
    MFMA_P(2);
    VMCNT(0);                      // drain A(15)+B(15); 0 outstanding
    BAR();
    READ_CVT_A(65536, 0); READ_B(147456);
    MFMA_P(0);
    BAR();
    READ_CVT_A(65536, 2);
    MFMA_P(2);

    // ---- epilogue ----
    const int bIdx = blockM >> 11;             // 256-row block, one batch
    float bp[4], tq[4], vv[4];
    #pragma unroll
    for (int nf = 0; nf < 4; nf++) {
        const int col = blockN + wn * 64 + nf * 16 + l15;
        bp[nf] = bpre[col];
        tq[nf] = tgt[(size_t)bIdx * NN + col];
        vv[nf] = vvec[col];
    }
    const int gr0 = blockM + wm * 64 + ((lane >> 4) << 2);
    const int colBase = blockN + wn * 64 + l15;
    float* epart = energy16 + (size_t)(nTile * 2 + wn) * MM;

    #pragma unroll
    for (int mf = 0; mf < 4; mf++) {
        #pragma unroll
        for (int j = 0; j < 4; j++) {
            const size_t rg = (size_t)gr0 + mf * 16 + j;
            float* prow = pre + rg * NN + colBase;
            float e = 0.f;
            #pragma unroll
            for (int nf = 0; nf < 4; nf++) {
                const float p = acc[mf][nf][j] + bp[nf];
                __builtin_nontemporal_store(p, &prow[nf * 16]);  // r14/16 total-best
                e += tanh_fast(p + tq[nf]) * vv[nf];
            }
            e += __shfl_xor(e, 1);
            e += __shfl_xor(e, 2);
            e += __shfl_xor(e, 4);
            e += __shfl_xor(e, 8);
            if (l15 == 0) epart[rg] = e;       // plain store, unique index
        }
    }
#undef STAGE_AT
#undef STAGE_BT
#undef READ_CVT_A
#undef READ_B
#undef MFMA_P
#undef BAR
#undef VMCNT
}

// ---------------------------------------------------------------------------
// Kernel 3: softmax over S per batch; energy = sum of 16 partials.
// ---------------------------------------------------------------------------
__global__ void softmax_kernel(const float* __restrict__ energy16,
                               float* __restrict__ score) {
    const int b = blockIdx.x, t = threadIdx.x;
    const int w = t >> 6, lane = t & 63;
    const size_t base = (size_t)b * SS;
    float x[8] = {0.f, 0.f, 0.f, 0.f, 0.f, 0.f, 0.f, 0.f};
    #pragma unroll
    for (int p = 0; p < 16; p++) {
        const float4* e4 = (const float4*)(energy16 + (size_t)p * MM + base);
        float4 v0 = e4[t * 2], v1 = e4[t * 2 + 1];
        x[0] += v0.x; x[1] += v0.y; x[2] += v0.z; x[3] += v0.w;
        x[4] += v1.x; x[5] += v1.y; x[6] += v1.z; x[7] += v1.w;
    }

    float mx = x[0];
    #pragma unroll
    for (int i = 1; i < 8; i++) mx = fmaxf(mx, x[i]);
    #pragma unroll
    for (int o = 32; o; o >>= 1) mx = fmaxf(mx, __shfl_xor(mx, o));
    __shared__ float rmax[4], rsum[4];
    if (lane == 0) rmax[w] = mx;
    __syncthreads();
    mx = fmaxf(fmaxf(rmax[0], rmax[1]), fmaxf(rmax[2], rmax[3]));

    float s = 0.f;
    #pragma unroll
    for (int i = 0; i < 8; i++) { x[i] = __expf(x[i] - mx); s += x[i]; }
    #pragma unroll
    for (int o = 32; o; o >>= 1) s += __shfl_xor(s, o);
    if (lane == 0) rsum[w] = s;
    __syncthreads();
    s = rsum[0] + rsum[1] + rsum[2] + rsum[3];
    const float inv = 1.0f / s;

    float* sc = score + base + t * 8;
    #pragma unroll
    for (int i = 0; i < 8; i++) sc[i] = x[i] * inv;
}

// ---------------------------------------------------------------------------
// Kernel 4: weightedContext partials from f32 ctx (nontemporal read-once
// stream, no atomics). wcpart[scnk][b][d].
// ---------------------------------------------------------------------------
__global__ void wctx_kernel(const float* __restrict__ ctx,
                            const float* __restrict__ score,
                            float* __restrict__ wcpart) {
    const int b = blockIdx.x, scnk = blockIdx.y, t = threadIdx.x;
    __shared__ float ss[256];
    ss[t] = score[(size_t)b * SS + scnk * 256 + t];
    __syncthreads();
    const f32x4* cr = (const f32x4*)(ctx + ((size_t)b * SS + (size_t)scnk * 256) * KK) + t;
    f32x4 a = {0.f, 0.f, 0.f, 0.f};
    #pragma unroll 4
    for (int s = 0; s < 256; s++) {
        const f32x4 c = __builtin_nontemporal_load(&cr[(size_t)s * 256]);
        const float wgt = ss[s];
        a += wgt * c;
    }
    float* o = wcpart + (size_t)scnk * (BB * KK) + (size_t)b * KK + t * 4;
    *(f32x4*)o = a;
}

// ---------------------------------------------------------------------------
// Kernel 4b: reduce 8 partials -> wc. 65536 elements, grid 64.
// ---------------------------------------------------------------------------
__global__ void wc_reduce_kernel(const float* __restrict__ wcpart,
                                 float* __restrict__ wc) {
    const int i = blockIdx.x * 1024 + threadIdx.x * 4;
    f32x4 s = {0.f, 0.f, 0.f, 0.f};
    #pragma unroll
    for (int p = 0; p < 8; p++) {
        const f32x4 v = *(const f32x4*)&wcpart[(size_t)p * (BB * KK) + i];
        s += v;
    }
    *(f32x4*)&wc[i] = s;
}

// ---------------------------------------------------------------------------
extern "C" void kernel_launch(void* const* d_in, const int* in_sizes, int n_in,
                              void* d_out, int out_size, void* d_ws, size_t ws_size,
                              hipStream_t stream) {
    const float* input = (const float*)d_in[0];   // [64,1024]
    const float* ctx   = (const float*)d_in[1];   // [64,2048,1024]
    const float* W_pre = (const float*)d_in[2];   // [1024,1024]
    const float* b_pre = (const float*)d_in[3];   // [1024]
    const float* W_q   = (const float*)d_in[4];   // [1024,1024]
    const float* v     = (const float*)d_in[5];   // [1024]

    float* out   = (float*)d_out;
    float* wc    = out;                      // [64,1024]   = 65536
    float* score = out + 65536;              // [64,2048]   = 131072
    float* pre   = out + 65536 + 131072;     // [64,2048,1024]

    // ws layout: tgt 256KB | energy16 8MB | wpb 2MB | wcpart 2MB (~12.6MB)
    float* tgt      = (float*)d_ws;                                 // 65536 f32
    float* energy16 = (float*)((char*)d_ws + 262144);               // 16*MM f32
    __hip_bfloat16* wpb = (__hip_bfloat16*)((char*)d_ws + 262144
                                            + (size_t)16 * MM * 4);
    float* wcpart   = (float*)((char*)d_ws + 262144
                               + (size_t)16 * MM * 4 + 2097152);    // 8*BB*KK

    targetT_kernel<<<dim3(BB, 4), 256, 0, stream>>>(input, W_q, tgt);
    cvt_bf16_kernel<<<512, 256, 0, stream>>>(W_pre, wpb, NN * KK / 8);

    gemm_f32a_kernel<<<dim3((MM / 256) * 8), 512, 0, stream>>>(
        ctx, wpb, b_pre, tgt, v, pre, energy16);

    softmax_kernel<<<dim3(BB), 256, 0, stream>>>(energy16, score);

    wctx_kernel<<<dim3(BB, 8), 256, 0, stream>>>(ctx, score, wcpart);
    wc_reduce_kernel<<<64, 256, 0, stream>>>(wcpart, wc);
}

// Round 18
// 549.303 us; speedup vs baseline: 1.2979x; 1.2979x over previous
//
#include <hip/hip_runtime.h>
#include <hip/hip_bf16.h>

// Problem constants
#define BB   64
#define SS   2048
#define MM   (BB*SS)      // 131072
#define NN   1024         // A
#define KK   1024         // AD = QD

typedef short bf16x8s __attribute__((ext_vector_type(8)));
typedef float f32x4   __attribute__((ext_vector_type(4)));
typedef unsigned short u16x4 __attribute__((ext_vector_type(4)));

__device__ __forceinline__ short f2bf(float f) {
    union { __hip_bfloat16 h; short s; } u;
    u.h = __float2bfloat16(f);
    return u.s;
}

__device__ __forceinline__ bf16x8s cvt8v(f32x4 a, f32x4 b) {
    bf16x8s r;
    r[0] = f2bf(a[0]); r[1] = f2bf(a[1]); r[2] = f2bf(a[2]); r[3] = f2bf(a[3]);
    r[4] = f2bf(b[0]); r[5] = f2bf(b[1]); r[6] = f2bf(b[2]); r[7] = f2bf(b[3]);
    return r;
}

__device__ __forceinline__ bf16x8s cvt8(float4 a, float4 b) {
    bf16x8s r;
    r[0] = f2bf(a.x); r[1] = f2bf(a.y); r[2] = f2bf(a.z); r[3] = f2bf(a.w);
    r[4] = f2bf(b.x); r[5] = f2bf(b.y); r[6] = f2bf(b.z); r[7] = f2bf(b.w);
    return r;
}

__device__ __forceinline__ float tanh_fast(float x) {
    x = fminf(8.0f, fmaxf(-8.0f, x));
    float e = __expf(2.0f * x);
    return 1.0f - 2.0f * __builtin_amdgcn_rcpf(e + 1.0f);
}

__device__ __forceinline__ void load_lds16(const void* g, void* l) {
    __builtin_amdgcn_global_load_lds(
        (const __attribute__((address_space(1))) unsigned int*)g,
        (__attribute__((address_space(3))) unsigned int*)l,
        16, 0, 0);
}

// ---------------------------------------------------------------------------
// Kernel 0: f32 -> bf16 convert. NT LOADS (ctx is read-once here) but
// REGULAR stores: ctxb is re-read by gemm (268MB) + wctx (268MB) right
// after -- let it allocate in L2/L3. (r17 insight: nt-store of a buffer
// that is immediately re-read defeats the cache.)
// ---------------------------------------------------------------------------
__global__ void cvt_bf16_kernel(const float* __restrict__ src,
                                __hip_bfloat16* __restrict__ dst, int n8) {
    int i = blockIdx.x * blockDim.x + threadIdx.x;
    const int stride = gridDim.x * blockDim.x;
    const f32x4* s4 = (const f32x4*)src;
    bf16x8s* d8 = (bf16x8s*)dst;
    for (; i < n8; i += stride) {
        f32x4 a = __builtin_nontemporal_load(&s4[i * 2]);
        f32x4 b = __builtin_nontemporal_load(&s4[i * 2 + 1]);
        d8[i] = cvt8v(a, b);
    }
}

// ---------------------------------------------------------------------------
// Kernel 1: targetT[b][n] = sum_q input[b][q] * W_q[n][q]
// ---------------------------------------------------------------------------
__global__ void targetT_kernel(const float* __restrict__ input,
                               const float* __restrict__ W_q,
                               float* __restrict__ tgt) {
    __shared__ float inp[KK];
    const int t = threadIdx.x;
    const int b = blockIdx.x;
    const float* inRow = input + (size_t)b * KK;
    for (int i = t; i < KK; i += 256) inp[i] = inRow[i];
    __syncthreads();
    const int w = t >> 6, lane = t & 63;
    const int nbase = blockIdx.y * 256 + w * 64;
    for (int i = 0; i < 64; i++) {
        const int n = nbase + i;
        const float* wq = W_q + (size_t)n * KK;
        float a = 0.f;
        #pragma unroll
        for (int j = 0; j < 16; j++) a += wq[lane + 64 * j] * inp[lane + 64 * j];
        #pragma unroll
        for (int o = 32; o; o >>= 1) a += __shfl_xor(a, o);
        if (lane == 0) tgt[(size_t)b * NN + n] = a;
    }
}

// ---------------------------------------------------------------------------
// Kernel 2: 4-phase 256x256 bf16 GEMM + bias + pre-store + tanh + energy part.
// r16 config (measured total-best 546us): nt pre-stores, setprio clusters,
// each phase ONE scheduling region {reads; stage; MFMA; [vmcnt]} fenced only
// at barriers; counted vmcnt(4) ledger (verified r5-r16).
// ---------------------------------------------------------------------------
__global__ __launch_bounds__(512, 2) void gemm8_kernel(
    const __hip_bfloat16* __restrict__ ctxb,  // [rows][KK] bf16 chunk
    const __hip_bfloat16* __restrict__ wpb,   // [NN][KK]  bf16
    const float* __restrict__ bpre,           // [NN]
    const float* __restrict__ tgt,            // [BB][NN]
    const float* __restrict__ vvec,           // [NN]
    float* __restrict__ pre,                  // [MM][NN]
    float* __restrict__ energy4,              // [4][MM] partials
    int row0)                                 // global row offset of chunk
{
    __shared__ __align__(16) char lds[131072];
    // A: [buf*32768 + row*128 + col]            (256 rows x 128 B per buf)
    // B: [65536 + buf*32768 + row*128 + col]

    const int nwg  = gridDim.x;
    const int orig = blockIdx.x;
    const int swz  = (orig & 7) * (nwg >> 3) + (orig >> 3);
    const int mTile = swz >> 2;          // N-tiles = 4
    const int nTile = swz & 3;
    const int blockM = mTile * 256;      // chunk-local
    const int blockN = nTile * 256;

    const int t = threadIdx.x, w = t >> 6, lane = t & 63;
    const int wm = w >> 2, wn = w & 3;   // 2 x 4 waves
    const int l15 = lane & 15;

    // ---- staging addresses (pre-swizzled global source, linear LDS dest) ----
    const int r0  = t >> 3;                               // 0..63
    const int lc0 = ((t & 7) * 16) ^ ((r0 & 7) << 4);
    const char* aSrc = (const char*)ctxb + (size_t)(blockM + r0) * 2048 + lc0;
    const char* bSrc = (const char*)wpb  + (size_t)(blockN + r0) * 2048 + lc0;

    // Full-tile stage = 4 vmem instructions per wave.
#define STAGE_AF(buf, T) do { \
    load_lds16(aSrc +          (T)*128, &lds[(buf)*32768 +         w*1024]); \
    load_lds16(aSrc + 131072 + (T)*128, &lds[(buf)*32768 +  8192 + w*1024]); \
    load_lds16(aSrc + 262144 + (T)*128, &lds[(buf)*32768 + 16384 + w*1024]); \
    load_lds16(aSrc + 393216 + (T)*128, &lds[(buf)*32768 + 24576 + w*1024]); \
} while(0)
#define STAGE_BF(buf, T) do { \
    load_lds16(bSrc +          (T)*128, &lds[65536 + (buf)*32768 +         w*1024]); \
    load_lds16(bSrc + 131072 + (T)*128, &lds[65536 + (buf)*32768 +  8192 + w*1024]); \
    load_lds16(bSrc + 262144 + (T)*128, &lds[65536 + (buf)*32768 + 16384 + w*1024]); \
    load_lds16(bSrc + 393216 + (T)*128, &lds[65536 + (buf)*32768 + 24576 + w*1024]); \
} while(0)

    // ---- fragment read addressing ----
    const int c16 = (lane >> 4) * 16;
    const int xo  = (lane & 7) << 4;
    const int bk0 = c16 ^ xo;            // ks = 0
    const int bk1 = (64 + c16) ^ xo;     // ks = 1
    const int aBase = wm * 16384 + l15 * 128;
    const int bBase = 65536 + wn * 8192 + l15 * 128;

    bf16x8s curA[4][2], Bf[4][2];

#define READ_A(buf, mbase) do { \
    _Pragma("unroll") \
    for (int mf = 0; mf < 4; mf++) { \
        curA[mf][0] = *(const bf16x8s*)&lds[(buf)*32768 + aBase + ((mbase)+mf)*2048 + bk0]; \
        curA[mf][1] = *(const bf16x8s*)&lds[(buf)*32768 + aBase + ((mbase)+mf)*2048 + bk1]; \
    } } while(0)
#define READ_B(buf) do { \
    _Pragma("unroll") \
    for (int nf = 0; nf < 4; nf++) { \
        Bf[nf][0] = *(const bf16x8s*)&lds[(buf)*32768 + bBase + (nf)*2048 + bk0]; \
        Bf[nf][1] = *(const bf16x8s*)&lds[(buf)*32768 + bBase + (nf)*2048 + bk1]; \
    } } while(0)

    f32x4 acc[8][4];
    #pragma unroll
    for (int m = 0; m < 8; m++)
        #pragma unroll
        for (int n = 0; n < 4; n++)
            acc[m][n] = f32x4{0.f, 0.f, 0.f, 0.f};

#define MFMA_H(mbase) do { \
    __builtin_amdgcn_s_setprio(1); \
    _Pragma("unroll") \
    for (int ks = 0; ks < 2; ks++) \
        _Pragma("unroll") \
        for (int mf = 0; mf < 4; mf++) \
            _Pragma("unroll") \
            for (int nf = 0; nf < 4; nf++) \
                acc[(mbase)+mf][nf] = __builtin_amdgcn_mfma_f32_16x16x32_bf16( \
                    curA[mf][ks], Bf[nf][ks], acc[(mbase)+mf][nf], 0, 0, 0); \
    __builtin_amdgcn_s_setprio(0); \
} while(0)

#define BAR() do { __builtin_amdgcn_sched_barrier(0); \
    __builtin_amdgcn_s_barrier(); \
    __builtin_amdgcn_sched_barrier(0); } while(0)
#define VMCNT(n) asm volatile("s_waitcnt vmcnt(" #n ")")

    // ---- prologue: A(0),B(0) -> buf0; B(1) -> buf1 (12 loads/wave) ----
    STAGE_AF(0, 0);
    STAGE_BF(0, 0);
    STAGE_BF(1, 1);
    VMCNT(4);                      // A(0),B(0) landed; B(1) in flight
    BAR();

    // K-tiles 0..15; iteration i computes tiles e=2i (buf0), o=2i+1 (buf1).
    #pragma unroll 1
    for (int i = 0; i < 7; i++) {
        const int To = 2 * i + 1, Te2 = 2 * i + 2, To2 = 2 * i + 3;
        // Ph1
        READ_A(0, 0); READ_B(0);
        STAGE_AF(1, To);
        MFMA_H(0);
        BAR();
        // Ph2
        READ_A(0, 4);
        STAGE_BF(0, Te2);
        MFMA_H(4);
        VMCNT(4);                  // A(o),B(o) landed; B(e+2) in flight
        BAR();
        // Ph3
        READ_A(1, 0); READ_B(1);
        STAGE_AF(0, Te2);
        MFMA_H(0);
        BAR();
        // Ph4
        READ_A(1, 4);
        STAGE_BF(1, To2);
        MFMA_H(4);
        VMCNT(4);                  // A(e+2),B(e+2) landed; B(o+2) in flight
        BAR();
    }

    // ---- peeled last iteration (tiles 14 buf0, 15 buf1) ----
    READ_A(0, 0); READ_B(0);
    STAGE_AF(1, 15);               // A(15) still needs staging
    MFMA_H(0);
    BAR();
    READ_A(0, 4);
    MFMA_H(4);
    VMCNT(0);                      // drain A(15),B(15); 0 outstanding
    BAR();
    READ_A(1, 0); READ_B(1);
    MFMA_H(0);
    BAR();
    READ_A(1, 4);
    MFMA_H(4);

    // ---- epilogue ----
    const int bIdx = (row0 + blockM) >> 11;   // all 256 rows share one batch
    float bp[4], tq[4], vv[4];
    #pragma unroll
    for (int nf = 0; nf < 4; nf++) {
        const int col = blockN + wn * 64 + nf * 16 + l15;
        bp[nf] = bpre[col];
        tq[nf] = tgt[(size_t)bIdx * NN + col];
        vv[nf] = vvec[col];
    }
    const int gr0 = blockM + wm * 128 + ((lane >> 4) << 2);
    const int colBase = blockN + wn * 64 + l15;
    float* epart = energy4 + (size_t)nTile * MM;

    #pragma unroll
    for (int mf = 0; mf < 8; mf++) {
        #pragma unroll
        for (int j = 0; j < 4; j++) {
            const size_t rg = (size_t)row0 + gr0 + mf * 16 + j;
            float* prow = pre + rg * NN + colBase;
            float e = 0.f;
            #pragma unroll
            for (int nf = 0; nf < 4; nf++) {
                const float p = acc[mf][nf][j] + bp[nf];
                __builtin_nontemporal_store(p, &prow[nf * 16]);  // r14/16 total-best
                e += tanh_fast(p + tq[nf]) * vv[nf];
            }
            e += __shfl_xor(e, 1);
            e += __shfl_xor(e, 2);
            e += __shfl_xor(e, 4);
            e += __shfl_xor(e, 8);
            if (l15 == 0) epart[rg] = e;     // plain store, no atomic
        }
    }
#undef STAGE_AF
#undef STAGE_BF
#undef READ_A
#undef READ_B
#undef MFMA_H
#undef BAR
#undef VMCNT
}

// ---------------------------------------------------------------------------
// Kernel 2 (fallback, ws too small): f32 GEMM, atomics into energy4[0].
// ---------------------------------------------------------------------------
__global__ __launch_bounds__(256, 2) void gemm_energy_kernel(
    const float* __restrict__ ctx, const float* __restrict__ wpre,
    const float* __restrict__ bpre, const float* __restrict__ tgt,
    const float* __restrict__ vvec, float* __restrict__ pre,
    float* __restrict__ energy4)
{
    __shared__ __align__(16) float As[128 * 32];
    __shared__ __align__(16) float Bs[128 * 32];

    const int orig = blockIdx.x;
    const int swz  = (orig & 7) * 1024 + (orig >> 3);
    const int mTile = swz >> 3;
    const int nTile = swz & 7;
    const size_t blockM = (size_t)mTile * 128;
    const int    blockN = nTile * 128;

    const int t = threadIdx.x, w = t >> 6, lane = t & 63;

    size_t aoff[4], boff[4];
    #pragma unroll
    for (int i = 0; i < 4; i++) {
        const int bb    = i * 4096 + w * 1024 + lane * 16;
        const int row   = bb >> 7;
        const int physc = bb & 127;
        const int logc  = physc ^ ((row & 7) << 4);
        aoff[i] = (blockM + (size_t)row) * (KK * 4) + logc;
        boff[i] = ((size_t)(blockN + row)) * (KK * 4) + logc;
    }
    const char* ctxB  = (const char*)ctx;
    const char* wpreB = (const char*)wpre;

    const int wm = (w >> 1) * 64, wn = (w & 1) * 64;

    int fa0[4], fa1[4], fb0[4], fb1[4];
    const int c0 = (lane >> 4) * 32;
    #pragma unroll
    for (int m = 0; m < 4; m++) {
        const int rA = wm + m * 16 + (lane & 15);
        const int sA = (rA & 7) << 4;
        fa0[m] = rA * 128 + (c0 ^ sA);
        fa1[m] = rA * 128 + ((c0 + 16) ^ sA);
        const int rB = wn + m * 16 + (lane & 15);
        const int sB = (rB & 7) << 4;
        fb0[m] = rB * 128 + (c0 ^ sB);
        fb1[m] = rB * 128 + ((c0 + 16) ^ sB);
    }

    f32x4 acc[4][4];
    #pragma unroll
    for (int m = 0; m < 4; m++)
        #pragma unroll
        for (int n = 0; n < 4; n++)
            acc[m][n] = f32x4{0.f, 0.f, 0.f, 0.f};

    for (int kt = 0; kt < KK / 32; kt++) {
        __syncthreads();
        #pragma unroll
        for (int i = 0; i < 4; i++) {
            load_lds16(ctxB  + aoff[i] + (size_t)kt * 128,
                       (char*)As + i * 4096 + w * 1024);
            load_lds16(wpreB + boff[i] + (size_t)kt * 128,
                       (char*)Bs + i * 4096 + w * 1024);
        }
        __syncthreads();

        bf16x8s af[4], bfr[4];
        #pragma unroll
        for (int m = 0; m < 4; m++) {
            float4 x0 = *(const float4*)((const char*)As + fa0[m]);
            float4 x1 = *(const float4*)((const char*)As + fa1[m]);
            af[m] = cvt8(x0, x1);
            float4 y0 = *(const float4*)((const char*)Bs + fb0[m]);
            float4 y1 = *(const float4*)((const char*)Bs + fb1[m]);
            bfr[m] = cvt8(y0, y1);
        }
        #pragma unroll
        for (int m = 0; m < 4; m++)
            #pragma unroll
            for (int n = 0; n < 4; n++)
                acc[m][n] = __builtin_amdgcn_mfma_f32_16x16x32_bf16(
                    af[m], bfr[n], acc[m][n], 0, 0, 0);
    }

    const int bIdx = (int)(blockM >> 11);
    float bp[4], tq[4], vv[4];
    #pragma unroll
    for (int n = 0; n < 4; n++) {
        const int col = blockN + wn + n * 16 + (lane & 15);
        bp[n] = bpre[col];
        tq[n] = tgt[(size_t)bIdx * NN + col];
        vv[n] = vvec[col];
    }
    const int colBase = blockN + wn + (lane & 15);

    #pragma unroll
    for (int m = 0; m < 4; m++) {
        const size_t rbase = blockM + wm + m * 16 + ((lane >> 4) << 2);
        #pragma unroll
        for (int j = 0; j < 4; j++) {
            const size_t rg = rbase + j;
            float* prow = pre + rg * NN + colBase;
            float e = 0.f;
            #pragma unroll
            for (int n = 0; n < 4; n++) {
                const float p = acc[m][n][j] + bp[n];
                prow[n * 16] = p;
                e += tanh_fast(p + tq[n]) * vv[n];
            }
            e += __shfl_xor(e, 1);
            e += __shfl_xor(e, 2);
            e += __shfl_xor(e, 4);
            e += __shfl_xor(e, 8);
            if ((lane & 15) == 0) atomicAdd(&energy4[rg], e);
        }
    }
}

// ---------------------------------------------------------------------------
// Kernel 3: softmax over S per batch; energy = sum of 4 partials.
// ---------------------------------------------------------------------------
__global__ void softmax_kernel(const float* __restrict__ energy4,
                               float* __restrict__ score) {
    const int b = blockIdx.x, t = threadIdx.x;
    const int w = t >> 6, lane = t & 63;
    const size_t base = (size_t)b * SS;
    float x[8] = {0.f, 0.f, 0.f, 0.f, 0.f, 0.f, 0.f, 0.f};
    #pragma unroll
    for (int p = 0; p < 4; p++) {
        const float4* e4 = (const float4*)(energy4 + (size_t)p * MM + base);
        float4 v0 = e4[t * 2], v1 = e4[t * 2 + 1];
        x[0] += v0.x; x[1] += v0.y; x[2] += v0.z; x[3] += v0.w;
        x[4] += v1.x; x[5] += v1.y; x[6] += v1.z; x[7] += v1.w;
    }

    float mx = x[0];
    #pragma unroll
    for (int i = 1; i < 8; i++) mx = fmaxf(mx, x[i]);
    #pragma unroll
    for (int o = 32; o; o >>= 1) mx = fmaxf(mx, __shfl_xor(mx, o));
    __shared__ float rmax[4], rsum[4];
    if (lane == 0) rmax[w] = mx;
    __syncthreads();
    mx = fmaxf(fmaxf(rmax[0], rmax[1]), fmaxf(rmax[2], rmax[3]));

    float s = 0.f;
    #pragma unroll
    for (int i = 0; i < 8; i++) { x[i] = __expf(x[i] - mx); s += x[i]; }
    #pragma unroll
    for (int o = 32; o; o >>= 1) s += __shfl_xor(s, o);
    if (lane == 0) rsum[w] = s;
    __syncthreads();
    s = rsum[0] + rsum[1] + rsum[2] + rsum[3];
    const float inv = 1.0f / s;

    float* sc = score + base + t * 8;
    #pragma unroll
    for (int i = 0; i < 8; i++) sc[i] = x[i] * inv;
}

// ---------------------------------------------------------------------------
// Kernel 4a: weightedContext partials from bf16 ctx copy (no atomics,
// nontemporal ctxb loads -- read-once stream at this point).
// ---------------------------------------------------------------------------
__global__ void wctx_bf16_kernel(const __hip_bfloat16* __restrict__ ctxb,
                                 const float* __restrict__ score,
                                 float* __restrict__ wcpart) {
    const int b = blockIdx.x, scnk = blockIdx.y, t = threadIdx.x;
    __shared__ float ss[256];
    ss[t] = score[(size_t)b * SS + scnk * 256 + t];
    __syncthreads();
    const u16x4* cr = (const u16x4*)(ctxb + ((size_t)b * SS + (size_t)scnk * 256) * KK) + t;
    float4 a = {0.f, 0.f, 0.f, 0.f};
    #pragma unroll 4
    for (int s = 0; s < 256; s++) {
        const u16x4 c = __builtin_nontemporal_load(&cr[(size_t)s * 256]);
        const float wgt = ss[s];
        a.x += wgt * __uint_as_float((unsigned)c[0] << 16);
        a.y += wgt * __uint_as_float((unsigned)c[1] << 16);
        a.z += wgt * __uint_as_float((unsigned)c[2] << 16);
        a.w += wgt * __uint_as_float((unsigned)c[3] << 16);
    }
    float* o = wcpart + (size_t)scnk * (BB * KK) + (size_t)b * KK + t * 4;
    o[0] = a.x; o[1] = a.y; o[2] = a.z; o[3] = a.w;
}

// ---------------------------------------------------------------------------
// Kernel 4a2: reduce 8 partials -> wc.  65536 elements, grid 64.
// ---------------------------------------------------------------------------
__global__ void wc_reduce_kernel(const float* __restrict__ wcpart,
                                 float* __restrict__ wc) {
    const int i = blockIdx.x * 1024 + threadIdx.x * 4;
    f32x4 s = {0.f, 0.f, 0.f, 0.f};
    #pragma unroll
    for (int p = 0; p < 8; p++) {
        const f32x4 v = *(const f32x4*)&wcpart[(size_t)p * (BB * KK) + i];
        s += v;
    }
    *(f32x4*)&wc[i] = s;
}

// ---------------------------------------------------------------------------
// Kernel 4b: f32 fallback (atomics; needs wc pre-zeroed).
// ---------------------------------------------------------------------------
__global__ void wctx_kernel(const float* __restrict__ ctx,
                            const float* __restrict__ score,
                            float* __restrict__ wc) {
    const int b = blockIdx.x, scnk = blockIdx.y, t = threadIdx.x;
    __shared__ float ss[256];
    ss[t] = score[(size_t)b * SS + scnk * 256 + t];
    __syncthreads();
    const float4* cr = (const float4*)(ctx + ((size_t)b * SS + (size_t)scnk * 256) * KK) + t;
    float4 a = {0.f, 0.f, 0.f, 0.f};
    #pragma unroll 4
    for (int s = 0; s < 256; s++) {
        const float4 c = cr[(size_t)s * 256];
        const float wgt = ss[s];
        a.x += wgt * c.x; a.y += wgt * c.y; a.z += wgt * c.z; a.w += wgt * c.w;
    }
    float* o = wc + (size_t)b * KK + t * 4;
    atomicAdd(o + 0, a.x);
    atomicAdd(o + 1, a.y);
    atomicAdd(o + 2, a.z);
    atomicAdd(o + 3, a.w);
}

// ---------------------------------------------------------------------------
extern "C" void kernel_launch(void* const* d_in, const int* in_sizes, int n_in,
                              void* d_out, int out_size, void* d_ws, size_t ws_size,
                              hipStream_t stream) {
    const float* input = (const float*)d_in[0];   // [64,1024]
    const float* ctx   = (const float*)d_in[1];   // [64,2048,1024]
    const float* W_pre = (const float*)d_in[2];   // [1024,1024]
    const float* b_pre = (const float*)d_in[3];   // [1024]
    const float* W_q   = (const float*)d_in[4];   // [1024,1024]
    const float* v     = (const float*)d_in[5];   // [1024]

    float* out   = (float*)d_out;
    float* wc    = out;                      // [64,1024]   = 65536
    float* score = out + 65536;              // [64,2048]   = 131072
    float* pre   = out + 65536 + 131072;     // [64,2048,1024]

    // ws layout: tgt 256KB | energy4 2MB | wpb 2MB | wcpart 2MB | ctxb chunk
    float* tgt     = (float*)d_ws;                                   // 65536 f32
    float* energy4 = (float*)((char*)d_ws + 262144);                 // 4*MM f32
    __hip_bfloat16* wpb = (__hip_bfloat16*)((char*)d_ws + 262144 + 2097152);
    float* wcpart  = (float*)((char*)d_ws + 262144 + 2097152 + 2097152); // 8*BB*KK f32
    __hip_bfloat16* ctxb = (__hip_bfloat16*)((char*)d_ws + 262144 + 2097152
                                             + 2097152 + 2097152);

    long long avail = (long long)ws_size - 262144LL - 3 * 2097152LL;
    long long cr = avail > 0 ? (avail / (KK * 2)) : 0;
    cr &= ~511LL;
    int chunk_rows = (int)(cr > MM ? MM : cr);

    targetT_kernel<<<dim3(BB, 4), 256, 0, stream>>>(input, W_q, tgt);

    if (chunk_rows >= 512) {
        cvt_bf16_kernel<<<512, 256, 0, stream>>>(W_pre, wpb, NN * KK / 8);
        for (int r0 = 0; r0 < MM; r0 += chunk_rows) {
            const int rows = (MM - r0) < chunk_rows ? (MM - r0) : chunk_rows;
            const int n8 = rows * KK / 8;
            const int cgrid = (n8 + 255) / 256 > 8192 ? 8192 : (n8 + 255) / 256;
            cvt_bf16_kernel<<<cgrid, 256, 0, stream>>>(
                ctx + (size_t)r0 * KK, ctxb, n8);
            gemm8_kernel<<<dim3((rows / 256) * 4), 512, 0, stream>>>(
                ctxb, wpb, b_pre, tgt, v, pre, energy4, r0);
        }
    } else {
        hipMemsetAsync(energy4, 0, (size_t)4 * MM * sizeof(float), stream);
        gemm_energy_kernel<<<dim3((MM / 128) * (NN / 128)), 256, 0, stream>>>(
            ctx, W_pre, b_pre, tgt, v, pre, energy4);
    }

    softmax_kernel<<<dim3(BB), 256, 0, stream>>>(energy4, score);

    if (chunk_rows >= MM) {
        wctx_bf16_kernel<<<dim3(BB, 8), 256, 0, stream>>>(ctxb, score, wcpart);
        wc_reduce_kernel<<<64, 256, 0, stream>>>(wcpart, wc);
    } else {
        hipMemsetAsync(wc, 0, (size_t)BB * KK * sizeof(float), stream);
        wctx_kernel<<<dim3(BB, 8), 256, 0, stream>>>(ctx, score, wc);
    }
}

// Round 19
// 544.415 us; speedup vs baseline: 1.3095x; 1.0090x over previous
//
#include <hip/hip_runtime.h>
#include <hip/hip_bf16.h>

// Problem constants
#define BB   64
#define SS   2048
#define MM   (BB*SS)      // 131072
#define NN   1024         // A
#define KK   1024         // AD = QD

typedef short bf16x8s __attribute__((ext_vector_type(8)));
typedef float f32x4   __attribute__((ext_vector_type(4)));
typedef unsigned short u16x4 __attribute__((ext_vector_type(4)));

__device__ __forceinline__ short f2bf(float f) {
    union { __hip_bfloat16 h; short s; } u;
    u.h = __float2bfloat16(f);
    return u.s;
}

__device__ __forceinline__ bf16x8s cvt8v(f32x4 a, f32x4 b) {
    bf16x8s r;
    r[0] = f2bf(a[0]); r[1] = f2bf(a[1]); r[2] = f2bf(a[2]); r[3] = f2bf(a[3]);
    r[4] = f2bf(b[0]); r[5] = f2bf(b[1]); r[6] = f2bf(b[2]); r[7] = f2bf(b[3]);
    return r;
}

__device__ __forceinline__ bf16x8s cvt8(float4 a, float4 b) {
    bf16x8s r;
    r[0] = f2bf(a.x); r[1] = f2bf(a.y); r[2] = f2bf(a.z); r[3] = f2bf(a.w);
    r[4] = f2bf(b.x); r[5] = f2bf(b.y); r[6] = f2bf(b.z); r[7] = f2bf(b.w);
    return r;
}

__device__ __forceinline__ float tanh_fast(float x) {
    x = fminf(8.0f, fmaxf(-8.0f, x));
    float e = __expf(2.0f * x);
    return 1.0f - 2.0f * __builtin_amdgcn_rcpf(e + 1.0f);
}

__device__ __forceinline__ void load_lds16(const void* g, void* l) {
    __builtin_amdgcn_global_load_lds(
        (const __attribute__((address_space(1))) unsigned int*)g,
        (__attribute__((address_space(3))) unsigned int*)l,
        16, 0, 0);
}

// ---------------------------------------------------------------------------
// Kernel 0: f32 -> bf16 convert, grid-stride, nontemporal (pure stream).
// [r16 measured-best configuration]
// ---------------------------------------------------------------------------
__global__ void cvt_bf16_kernel(const float* __restrict__ src,
                                __hip_bfloat16* __restrict__ dst, int n8) {
    int i = blockIdx.x * blockDim.x + threadIdx.x;
    const int stride = gridDim.x * blockDim.x;
    const f32x4* s4 = (const f32x4*)src;
    bf16x8s* d8 = (bf16x8s*)dst;
    for (; i < n8; i += stride) {
        f32x4 a = __builtin_nontemporal_load(&s4[i * 2]);
        f32x4 b = __builtin_nontemporal_load(&s4[i * 2 + 1]);
        __builtin_nontemporal_store(cvt8v(a, b), &d8[i]);
    }
}

// ---------------------------------------------------------------------------
// Kernel 1: targetT[b][n] = sum_q input[b][q] * W_q[n][q]
// ---------------------------------------------------------------------------
__global__ void targetT_kernel(const float* __restrict__ input,
                               const float* __restrict__ W_q,
                               float* __restrict__ tgt) {
    __shared__ float inp[KK];
    const int t = threadIdx.x;
    const int b = blockIdx.x;
    const float* inRow = input + (size_t)b * KK;
    for (int i = t; i < KK; i += 256) inp[i] = inRow[i];
    __syncthreads();
    const int w = t >> 6, lane = t & 63;
    const int nbase = blockIdx.y * 256 + w * 64;
    for (int i = 0; i < 64; i++) {
        const int n = nbase + i;
        const float* wq = W_q + (size_t)n * KK;
        float a = 0.f;
        #pragma unroll
        for (int j = 0; j < 16; j++) a += wq[lane + 64 * j] * inp[lane + 64 * j];
        #pragma unroll
        for (int o = 32; o; o >>= 1) a += __shfl_xor(a, o);
        if (lane == 0) tgt[(size_t)b * NN + n] = a;
    }
}

// ---------------------------------------------------------------------------
// Kernel 2: 4-phase 256x256 bf16 GEMM + bias + pre-store + tanh + energy part.
// r16 config (measured total-best 546us): nt pre-stores, setprio clusters,
// each phase ONE scheduling region {reads; stage; MFMA; [vmcnt]} fenced only
// at barriers; counted vmcnt(4) ledger (verified r5-r16).
// ---------------------------------------------------------------------------
__global__ __launch_bounds__(512, 2) void gemm8_kernel(
    const __hip_bfloat16* __restrict__ ctxb,  // [rows][KK] bf16 chunk
    const __hip_bfloat16* __restrict__ wpb,   // [NN][KK]  bf16
    const float* __restrict__ bpre,           // [NN]
    const float* __restrict__ tgt,            // [BB][NN]
    const float* __restrict__ vvec,           // [NN]
    float* __restrict__ pre,                  // [MM][NN]
    float* __restrict__ energy4,              // [4][MM] partials
    int row0)                                 // global row offset of chunk
{
    __shared__ __align__(16) char lds[131072];
    // A: [buf*32768 + row*128 + col]            (256 rows x 128 B per buf)
    // B: [65536 + buf*32768 + row*128 + col]

    const int nwg  = gridDim.x;
    const int orig = blockIdx.x;
    const int swz  = (orig & 7) * (nwg >> 3) + (orig >> 3);
    const int mTile = swz >> 2;          // N-tiles = 4
    const int nTile = swz & 3;
    const int blockM = mTile * 256;      // chunk-local
    const int blockN = nTile * 256;

    const int t = threadIdx.x, w = t >> 6, lane = t & 63;
    const int wm = w >> 2, wn = w & 3;   // 2 x 4 waves
    const int l15 = lane & 15;

    // ---- staging addresses (pre-swizzled global source, linear LDS dest) ----
    const int r0  = t >> 3;                               // 0..63
    const int lc0 = ((t & 7) * 16) ^ ((r0 & 7) << 4);
    const char* aSrc = (const char*)ctxb + (size_t)(blockM + r0) * 2048 + lc0;
    const char* bSrc = (const char*)wpb  + (size_t)(blockN + r0) * 2048 + lc0;

    // Full-tile stage = 4 vmem instructions per wave.
#define STAGE_AF(buf, T) do { \
    load_lds16(aSrc +          (T)*128, &lds[(buf)*32768 +         w*1024]); \
    load_lds16(aSrc + 131072 + (T)*128, &lds[(buf)*32768 +  8192 + w*1024]); \
    load_lds16(aSrc + 262144 + (T)*128, &lds[(buf)*32768 + 16384 + w*1024]); \
    load_lds16(aSrc + 393216 + (T)*128, &lds[(buf)*32768 + 24576 + w*1024]); \
} while(0)
#define STAGE_BF(buf, T) do { \
    load_lds16(bSrc +          (T)*128, &lds[65536 + (buf)*32768 +         w*1024]); \
    load_lds16(bSrc + 131072 + (T)*128, &lds[65536 + (buf)*32768 +  8192 + w*1024]); \
    load_lds16(bSrc + 262144 + (T)*128, &lds[65536 + (buf)*32768 + 16384 + w*1024]); \
    load_lds16(bSrc + 393216 + (T)*128, &lds[65536 + (buf)*32768 + 24576 + w*1024]); \
} while(0)

    // ---- fragment read addressing ----
    const int c16 = (lane >> 4) * 16;
    const int xo  = (lane & 7) << 4;
    const int bk0 = c16 ^ xo;            // ks = 0
    const int bk1 = (64 + c16) ^ xo;     // ks = 1
    const int aBase = wm * 16384 + l15 * 128;
    const int bBase = 65536 + wn * 8192 + l15 * 128;

    bf16x8s curA[4][2], Bf[4][2];

#define READ_A(buf, mbase) do { \
    _Pragma("unroll") \
    for (int mf = 0; mf < 4; mf++) { \
        curA[mf][0] = *(const bf16x8s*)&lds[(buf)*32768 + aBase + ((mbase)+mf)*2048 + bk0]; \
        curA[mf][1] = *(const bf16x8s*)&lds[(buf)*32768 + aBase + ((mbase)+mf)*2048 + bk1]; \
    } } while(0)
#define READ_B(buf) do { \
    _Pragma("unroll") \
    for (int nf = 0; nf < 4; nf++) { \
        Bf[nf][0] = *(const bf16x8s*)&lds[(buf)*32768 + bBase + (nf)*2048 + bk0]; \
        Bf[nf][1] = *(const bf16x8s*)&lds[(buf)*32768 + bBase + (nf)*2048 + bk1]; \
    } } while(0)

    f32x4 acc[8][4];
    #pragma unroll
    for (int m = 0; m < 8; m++)
        #pragma unroll
        for (int n = 0; n < 4; n++)
            acc[m][n] = f32x4{0.f, 0.f, 0.f, 0.f};

#define MFMA_H(mbase) do { \
    __builtin_amdgcn_s_setprio(1); \
    _Pragma("unroll") \
    for (int ks = 0; ks < 2; ks++) \
        _Pragma("unroll") \
        for (int mf = 0; mf < 4; mf++) \
            _Pragma("unroll") \
            for (int nf = 0; nf < 4; nf++) \
                acc[(mbase)+mf][nf] = __builtin_amdgcn_mfma_f32_16x16x32_bf16( \
                    curA[mf][ks], Bf[nf][ks], acc[(mbase)+mf][nf], 0, 0, 0); \
    __builtin_amdgcn_s_setprio(0); \
} while(0)

#define BAR() do { __builtin_amdgcn_sched_barrier(0); \
    __builtin_amdgcn_s_barrier(); \
    __builtin_amdgcn_sched_barrier(0); } while(0)
#define VMCNT(n) asm volatile("s_waitcnt vmcnt(" #n ")")

    // ---- prologue: A(0),B(0) -> buf0; B(1) -> buf1 (12 loads/wave) ----
    STAGE_AF(0, 0);
    STAGE_BF(0, 0);
    STAGE_BF(1, 1);
    VMCNT(4);                      // A(0),B(0) landed; B(1) in flight
    BAR();

    // K-tiles 0..15; iteration i computes tiles e=2i (buf0), o=2i+1 (buf1).
    #pragma unroll 1
    for (int i = 0; i < 7; i++) {
        const int To = 2 * i + 1, Te2 = 2 * i + 2, To2 = 2 * i + 3;
        // Ph1
        READ_A(0, 0); READ_B(0);
        STAGE_AF(1, To);
        MFMA_H(0);
        BAR();
        // Ph2
        READ_A(0, 4);
        STAGE_BF(0, Te2);
        MFMA_H(4);
        VMCNT(4);                  // A(o),B(o) landed; B(e+2) in flight
        BAR();
        // Ph3
        READ_A(1, 0); READ_B(1);
        STAGE_AF(0, Te2);
        MFMA_H(0);
        BAR();
        // Ph4
        READ_A(1, 4);
        STAGE_BF(1, To2);
        MFMA_H(4);
        VMCNT(4);                  // A(e+2),B(e+2) landed; B(o+2) in flight
        BAR();
    }

    // ---- peeled last iteration (tiles 14 buf0, 15 buf1) ----
    READ_A(0, 0); READ_B(0);
    STAGE_AF(1, 15);               // A(15) still needs staging
    MFMA_H(0);
    BAR();
    READ_A(0, 4);
    MFMA_H(4);
    VMCNT(0);                      // drain A(15),B(15); 0 outstanding
    BAR();
    READ_A(1, 0); READ_B(1);
    MFMA_H(0);
    BAR();
    READ_A(1, 4);
    MFMA_H(4);

    // ---- epilogue ----
    const int bIdx = (row0 + blockM) >> 11;   // all 256 rows share one batch
    float bp[4], tq[4], vv[4];
    #pragma unroll
    for (int nf = 0; nf < 4; nf++) {
        const int col = blockN + wn * 64 + nf * 16 + l15;
        bp[nf] = bpre[col];
        tq[nf] = tgt[(size_t)bIdx * NN + col];
        vv[nf] = vvec[col];
    }
    const int gr0 = blockM + wm * 128 + ((lane >> 4) << 2);
    const int colBase = blockN + wn * 64 + l15;
    float* epart = energy4 + (size_t)nTile * MM;

    #pragma unroll
    for (int mf = 0; mf < 8; mf++) {
        #pragma unroll
        for (int j = 0; j < 4; j++) {
            const size_t rg = (size_t)row0 + gr0 + mf * 16 + j;
            float* prow = pre + rg * NN + colBase;
            float e = 0.f;
            #pragma unroll
            for (int nf = 0; nf < 4; nf++) {
                const float p = acc[mf][nf][j] + bp[nf];
                __builtin_nontemporal_store(p, &prow[nf * 16]);  // r14/16 total-best
                e += tanh_fast(p + tq[nf]) * vv[nf];
            }
            e += __shfl_xor(e, 1);
            e += __shfl_xor(e, 2);
            e += __shfl_xor(e, 4);
            e += __shfl_xor(e, 8);
            if (l15 == 0) epart[rg] = e;     // plain store, no atomic
        }
    }
#undef STAGE_AF
#undef STAGE_BF
#undef READ_A
#undef READ_B
#undef MFMA_H
#undef BAR
#undef VMCNT
}

// ---------------------------------------------------------------------------
// Kernel 2 (fallback, ws too small): f32 GEMM, atomics into energy4[0].
// ---------------------------------------------------------------------------
__global__ __launch_bounds__(256, 2) void gemm_energy_kernel(
    const float* __restrict__ ctx, const float* __restrict__ wpre,
    const float* __restrict__ bpre, const float* __restrict__ tgt,
    const float* __restrict__ vvec, float* __restrict__ pre,
    float* __restrict__ energy4)
{
    __shared__ __align__(16) float As[128 * 32];
    __shared__ __align__(16) float Bs[128 * 32];

    const int orig = blockIdx.x;
    const int swz  = (orig & 7) * 1024 + (orig >> 3);
    const int mTile = swz >> 3;
    const int nTile = swz & 7;
    const size_t blockM = (size_t)mTile * 128;
    const int    blockN = nTile * 128;

    const int t = threadIdx.x, w = t >> 6, lane = t & 63;

    size_t aoff[4], boff[4];
    #pragma unroll
    for (int i = 0; i < 4; i++) {
        const int bb    = i * 4096 + w * 1024 + lane * 16;
        const int row   = bb >> 7;
        const int physc = bb & 127;
        const int logc  = physc ^ ((row & 7) << 4);
        aoff[i] = (blockM + (size_t)row) * (KK * 4) + logc;
        boff[i] = ((size_t)(blockN + row)) * (KK * 4) + logc;
    }
    const char* ctxB  = (const char*)ctx;
    const char* wpreB = (const char*)wpre;

    const int wm = (w >> 1) * 64, wn = (w & 1) * 64;

    int fa0[4], fa1[4], fb0[4], fb1[4];
    const int c0 = (lane >> 4) * 32;
    #pragma unroll
    for (int m = 0; m < 4; m++) {
        const int rA = wm + m * 16 + (lane & 15);
        const int sA = (rA & 7) << 4;
        fa0[m] = rA * 128 + (c0 ^ sA);
        fa1[m] = rA * 128 + ((c0 + 16) ^ sA);
        const int rB = wn + m * 16 + (lane & 15);
        const int sB = (rB & 7) << 4;
        fb0[m] = rB * 128 + (c0 ^ sB);
        fb1[m] = rB * 128 + ((c0 + 16) ^ sB);
    }

    f32x4 acc[4][4];
    #pragma unroll
    for (int m = 0; m < 4; m++)
        #pragma unroll
        for (int n = 0; n < 4; n++)
            acc[m][n] = f32x4{0.f, 0.f, 0.f, 0.f};

    for (int kt = 0; kt < KK / 32; kt++) {
        __syncthreads();
        #pragma unroll
        for (int i = 0; i < 4; i++) {
            load_lds16(ctxB  + aoff[i] + (size_t)kt * 128,
                       (char*)As + i * 4096 + w * 1024);
            load_lds16(wpreB + boff[i] + (size_t)kt * 128,
                       (char*)Bs + i * 4096 + w * 1024);
        }
        __syncthreads();

        bf16x8s af[4], bfr[4];
        #pragma unroll
        for (int m = 0; m < 4; m++) {
            float4 x0 = *(const float4*)((const char*)As + fa0[m]);
            float4 x1 = *(const float4*)((const char*)As + fa1[m]);
            af[m] = cvt8(x0, x1);
            float4 y0 = *(const float4*)((const char*)Bs + fb0[m]);
            float4 y1 = *(const float4*)((const char*)Bs + fb1[m]);
            bfr[m] = cvt8(y0, y1);
        }
        #pragma unroll
        for (int m = 0; m < 4; m++)
            #pragma unroll
            for (int n = 0; n < 4; n++)
                acc[m][n] = __builtin_amdgcn_mfma_f32_16x16x32_bf16(
                    af[m], bfr[n], acc[m][n], 0, 0, 0);
    }

    const int bIdx = (int)(blockM >> 11);
    float bp[4], tq[4], vv[4];
    #pragma unroll
    for (int n = 0; n < 4; n++) {
        const int col = blockN + wn + n * 16 + (lane & 15);
        bp[n] = bpre[col];
        tq[n] = tgt[(size_t)bIdx * NN + col];
        vv[n] = vvec[col];
    }
    const int colBase = blockN + wn + (lane & 15);

    #pragma unroll
    for (int m = 0; m < 4; m++) {
        const size_t rbase = blockM + wm + m * 16 + ((lane >> 4) << 2);
        #pragma unroll
        for (int j = 0; j < 4; j++) {
            const size_t rg = rbase + j;
            float* prow = pre + rg * NN + colBase;
            float e = 0.f;
            #pragma unroll
            for (int n = 0; n < 4; n++) {
                const float p = acc[m][n][j] + bp[n];
                prow[n * 16] = p;
                e += tanh_fast(p + tq[n]) * vv[n];
            }
            e += __shfl_xor(e, 1);
            e += __shfl_xor(e, 2);
            e += __shfl_xor(e, 4);
            e += __shfl_xor(e, 8);
            if ((lane & 15) == 0) atomicAdd(&energy4[rg], e);
        }
    }
}

// ---------------------------------------------------------------------------
// Kernel 3: softmax over S per batch; energy = sum of 4 partials.
// ---------------------------------------------------------------------------
__global__ void softmax_kernel(const float* __restrict__ energy4,
                               float* __restrict__ score) {
    const int b = blockIdx.x, t = threadIdx.x;
    const int w = t >> 6, lane = t & 63;
    const size_t base = (size_t)b * SS;
    float x[8] = {0.f, 0.f, 0.f, 0.f, 0.f, 0.f, 0.f, 0.f};
    #pragma unroll
    for (int p = 0; p < 4; p++) {
        const float4* e4 = (const float4*)(energy4 + (size_t)p * MM + base);
        float4 v0 = e4[t * 2], v1 = e4[t * 2 + 1];
        x[0] += v0.x; x[1] += v0.y; x[2] += v0.z; x[3] += v0.w;
        x[4] += v1.x; x[5] += v1.y; x[6] += v1.z; x[7] += v1.w;
    }

    float mx = x[0];
    #pragma unroll
    for (int i = 1; i < 8; i++) mx = fmaxf(mx, x[i]);
    #pragma unroll
    for (int o = 32; o; o >>= 1) mx = fmaxf(mx, __shfl_xor(mx, o));
    __shared__ float rmax[4], rsum[4];
    if (lane == 0) rmax[w] = mx;
    __syncthreads();
    mx = fmaxf(fmaxf(rmax[0], rmax[1]), fmaxf(rmax[2], rmax[3]));

    float s = 0.f;
    #pragma unroll
    for (int i = 0; i < 8; i++) { x[i] = __expf(x[i] - mx); s += x[i]; }
    #pragma unroll
    for (int o = 32; o; o >>= 1) s += __shfl_xor(s, o);
    if (lane == 0) rsum[w] = s;
    __syncthreads();
    s = rsum[0] + rsum[1] + rsum[2] + rsum[3];
    const float inv = 1.0f / s;

    float* sc = score + base + t * 8;
    #pragma unroll
    for (int i = 0; i < 8; i++) sc[i] = x[i] * inv;
}

// ---------------------------------------------------------------------------
// Kernel 4a: weightedContext partials from bf16 ctx copy (no atomics,
// nontemporal ctxb loads -- read-once stream).
// wcpart[scnk][b][d] <- sum over this chunk's 256 s values.
// ---------------------------------------------------------------------------
__global__ void wctx_bf16_kernel(const __hip_bfloat16* __restrict__ ctxb,
                                 const float* __restrict__ score,
                                 float* __restrict__ wcpart) {
    const int b = blockIdx.x, scnk = blockIdx.y, t = threadIdx.x;
    __shared__ float ss[256];
    ss[t] = score[(size_t)b * SS + scnk * 256 + t];
    __syncthreads();
    const u16x4* cr = (const u16x4*)(ctxb + ((size_t)b * SS + (size_t)scnk * 256) * KK) + t;
    float4 a = {0.f, 0.f, 0.f, 0.f};
    #pragma unroll 4
    for (int s = 0; s < 256; s++) {
        const u16x4 c = __builtin_nontemporal_load(&cr[(size_t)s * 256]);
        const float wgt = ss[s];
        a.x += wgt * __uint_as_float((unsigned)c[0] << 16);
        a.y += wgt * __uint_as_float((unsigned)c[1] << 16);
        a.z += wgt * __uint_as_float((unsigned)c[2] << 16);
        a.w += wgt * __uint_as_float((unsigned)c[3] << 16);
    }
    float* o = wcpart + (size_t)scnk * (BB * KK) + (size_t)b * KK + t * 4;
    o[0] = a.x; o[1] = a.y; o[2] = a.z; o[3] = a.w;
}

// ---------------------------------------------------------------------------
// Kernel 4a2: reduce 8 partials -> wc.  65536 elements, grid 64.
// ---------------------------------------------------------------------------
__global__ void wc_reduce_kernel(const float* __restrict__ wcpart,
                                 float* __restrict__ wc) {
    const int i = blockIdx.x * 1024 + threadIdx.x * 4;
    f32x4 s = {0.f, 0.f, 0.f, 0.f};
    #pragma unroll
    for (int p = 0; p < 8; p++) {
        const f32x4 v = *(const f32x4*)&wcpart[(size_t)p * (BB * KK) + i];
        s += v;
    }
    *(f32x4*)&wc[i] = s;
}

// ---------------------------------------------------------------------------
// Kernel 4b: f32 fallback (atomics; needs wc pre-zeroed).
// ---------------------------------------------------------------------------
__global__ void wctx_kernel(const float* __restrict__ ctx,
                            const float* __restrict__ score,
                            float* __restrict__ wc) {
    const int b = blockIdx.x, scnk = blockIdx.y, t = threadIdx.x;
    __shared__ float ss[256];
    ss[t] = score[(size_t)b * SS + scnk * 256 + t];
    __syncthreads();
    const float4* cr = (const float4*)(ctx + ((size_t)b * SS + (size_t)scnk * 256) * KK) + t;
    float4 a = {0.f, 0.f, 0.f, 0.f};
    #pragma unroll 4
    for (int s = 0; s < 256; s++) {
        const float4 c = cr[(size_t)s * 256];
        const float wgt = ss[s];
        a.x += wgt * c.x; a.y += wgt * c.y; a.z += wgt * c.z; a.w += wgt * c.w;
    }
    float* o = wc + (size_t)b * KK + t * 4;
    atomicAdd(o + 0, a.x);
    atomicAdd(o + 1, a.y);
    atomicAdd(o + 2, a.z);
    atomicAdd(o + 3, a.w);
}

// ---------------------------------------------------------------------------
extern "C" void kernel_launch(void* const* d_in, const int* in_sizes, int n_in,
                              void* d_out, int out_size, void* d_ws, size_t ws_size,
                              hipStream_t stream) {
    const float* input = (const float*)d_in[0];   // [64,1024]
    const float* ctx   = (const float*)d_in[1];   // [64,2048,1024]
    const float* W_pre = (const float*)d_in[2];   // [1024,1024]
    const float* b_pre = (const float*)d_in[3];   // [1024]
    const float* W_q   = (const float*)d_in[4];   // [1024,1024]
    const float* v     = (const float*)d_in[5];   // [1024]

    float* out   = (float*)d_out;
    float* wc    = out;                      // [64,1024]   = 65536
    float* score = out + 65536;              // [64,2048]   = 131072
    float* pre   = out + 65536 + 131072;     // [64,2048,1024]

    // ws layout: tgt 256KB | energy4 2MB | wpb 2MB | wcpart 2MB | ctxb chunk
    float* tgt     = (float*)d_ws;                                   // 65536 f32
    float* energy4 = (float*)((char*)d_ws + 262144);                 // 4*MM f32
    __hip_bfloat16* wpb = (__hip_bfloat16*)((char*)d_ws + 262144 + 2097152);
    float* wcpart  = (float*)((char*)d_ws + 262144 + 2097152 + 2097152); // 8*BB*KK f32
    __hip_bfloat16* ctxb = (__hip_bfloat16*)((char*)d_ws + 262144 + 2097152
                                             + 2097152 + 2097152);

    long long avail = (long long)ws_size - 262144LL - 3 * 2097152LL;
    long long cr = avail > 0 ? (avail / (KK * 2)) : 0;
    cr &= ~511LL;
    int chunk_rows = (int)(cr > MM ? MM : cr);

    targetT_kernel<<<dim3(BB, 4), 256, 0, stream>>>(input, W_q, tgt);

    if (chunk_rows >= 512) {
        cvt_bf16_kernel<<<512, 256, 0, stream>>>(W_pre, wpb, NN * KK / 8);
        for (int r0 = 0; r0 < MM; r0 += chunk_rows) {
            const int rows = (MM - r0) < chunk_rows ? (MM - r0) : chunk_rows;
            const int n8 = rows * KK / 8;
            const int cgrid = (n8 + 255) / 256 > 8192 ? 8192 : (n8 + 255) / 256;
            cvt_bf16_kernel<<<cgrid, 256, 0, stream>>>(
                ctx + (size_t)r0 * KK, ctxb, n8);
            gemm8_kernel<<<dim3((rows / 256) * 4), 512, 0, stream>>>(
                ctxb, wpb, b_pre, tgt, v, pre, energy4, r0);
        }
    } else {
        hipMemsetAsync(energy4, 0, (size_t)4 * MM * sizeof(float), stream);
        gemm_energy_kernel<<<dim3((MM / 128) * (NN / 128)), 256, 0, stream>>>(
            ctx, W_pre, b_pre, tgt, v, pre, energy4);
    }

    softmax_kernel<<<dim3(BB), 256, 0, stream>>>(energy4, score);

    if (chunk_rows >= MM) {
        wctx_bf16_kernel<<<dim3(BB, 8), 256, 0, stream>>>(ctxb, score, wcpart);
        wc_reduce_kernel<<<64, 256, 0, stream>>>(wcpart, wc);
    } else {
        hipMemsetAsync(wc, 0, (size_t)BB * KK * sizeof(float), stream);
        wctx_kernel<<<dim3(BB, 8), 256, 0, stream>>>(ctx, score, wc);
    }
}